// Round 12
// baseline (1534.513 us; speedup 1.0000x reference)
//
#include <hip/hip_runtime.h>
#include <math.h>

#define T_ 60
#define N_ 16384
#define C_ 5
#define H_ 20
#define G_ 80
#define HC_ 15
#define N0_ 3190
#define E0_ 31900
#define K_ 5

// workspace layout (float offsets)
#define OFF_SEQ   0
#define OFF_XH    (T_*N_*H_)            // 19,660,800
#define OFF_XHN   (OFF_XH + N_*H_)
#define OFF_NX0   (OFF_XHN + N_)
#define OFF_RX0   (OFF_NX0 + N0_)
#define OFF_TOP5  (OFF_RX0 + N0_)       // int[ N_*K_ ]
#define OFF_SUM1  (OFF_TOP5 + N_*K_)
#define OFF_CNT1  (OFF_SUM1 + N0_*H_)
#define OFF_OBASE (OFF_CNT1 + N0_)

__device__ __forceinline__ float sigf(float x) {
  return __fdividef(1.0f, 1.0f + __expf(-x));
}
__device__ __forceinline__ float tanhf_fast(float x) {
  float xc = fminf(fmaxf(x, -44.0f), 44.0f);
  float e = __expf(2.0f * xc);
  return __fdividef(e - 1.0f, e + 1.0f);
}

// ============================================================================
// LSTM layer "wpe" v2: WAVE-PER-ELEMENT + DISTRIBUTED BRANCHLESS ACTIVATION.
// Round-11 state: VGPR=48, 80% VALUBusy, clean FETCH, 310 us/layer; the gate
// phase (5 transcendental chains on 20-of-64 lanes + clamps) was ~half of
// per-step issue. Round-12 change:
//  - after the col-combine shuffles, EVERY lane holds raw rows rg*5..+4 and
//    each rg is one gate type -> lane (rg,cg) activates row rg*5+cg (cg0
//    also +4): <=2 chains/lane, all 64 lanes useful.
//  - branchless act(x) = m*sig(s*x)+a, (s,m,a)=(2,2,-1) tanh-rows rg8..11,
//    (1,1,0) sigmoid-rows; exp-saturation replaces clamps.
//  - u-phase: 4 LDS reads (activated gates), 2 fma, one tanh-of-c, stores.
//  - launch_bounds stays (256,2): rounds 6/10 proved raising min-occupancy
//    caps VGPR below need -> scratch spill. DO NOT raise.
// ============================================================================

#define LWV 160   // per-wave LDS region (floats): zb[48] | gr@64[80] | raw@144

template <bool FIRST>
__global__ void __launch_bounds__(256, 2) lstm_wpe_kernel(
    const float* __restrict__ xg,      // [T, N, 5] raw codes (FIRST only)
    const float* __restrict__ embw,    // [5, 20]              (FIRST only)
    const float* __restrict__ Wih,     // [80, 20] this layer
    const float* __restrict__ Whh,     // [80, 20]
    const float* __restrict__ bih,     // [80]
    const float* __restrict__ bhh,     // [80]
    float* __restrict__ seq) {         // in (!FIRST) and out: [T, N, 20]
  __shared__ __align__(16) float wst[3200];     // staged [80][40]
  __shared__ __align__(16) float wsh[4 * LWV];  // per-wave regions
  const int tid = threadIdx.x;

  for (int i = tid; i < 3200; i += 256) {
    int r = i / 40, col = i % 40;
    wst[i] = (col < 20) ? Wih[r * 20 + col] : Whh[r * 20 + (col - 20)];
  }
  __syncthreads();

  const int lane = tid & 63;
  const int w = tid >> 6;
  const int rg = lane >> 2;            // row group: rows rg*5..rg*5+4
  const int cg = lane & 3;             // col group: cols cg*10..cg*10+9
  const int n = (blockIdx.x << 2) + w; // this wave's element
  float* zb  = &wsh[w * LWV];          // z slots: [4 slots][12] (slot s = cols s*10..+9)
  float* gr  = &wsh[w * LWV + 64];     // ACTIVATED gates [80]
  float* raw = &wsh[w * LWV + 144];    // FIRST: 5 codes

  // ---- weight registers (pinned: opaque to the compiler => no remat) ----
  float wr[5][10];
  {
    const float* bp = &wst[(rg * 5) * 40 + cg * 10];
#pragma unroll
    for (int j = 0; j < 5; j++)
#pragma unroll
      for (int m = 0; m < 10; m++) wr[j][m] = bp[j * 40 + m];
  }
#pragma unroll
  for (int j = 0; j < 5; j++)
#pragma unroll
    for (int m = 0; m < 10; m++) asm volatile("" : "+v"(wr[j][m]));

  // ---- per-lane activation constants (gate type is uniform per rg) ----
  const bool useTanh = (rg >= 8 && rg < 12);      // rows 40..59 = gate g
  const float nS = useTanh ? -2.0f : -1.0f;       // -(input scale)
  const float mM = useTanh ?  2.0f :  1.0f;
  const float aA = useTanh ? -1.0f :  0.0f;
  const float bA = bih[rg * 5 + cg] + bhh[rg * 5 + cg];
  const float bB = bih[rg * 5 + 4] + bhh[rg * 5 + 4];   // cg==0 only
  float* grA = gr + rg * 5 + cg;
  float* grB = gr + rg * 5 + 4;

  const bool isU = (lane < 20);
  const int u = isU ? lane : 0;
  float e0 = 0, e1 = 0, e2 = 0, e3 = 0, e4 = 0;
  if (FIRST) {
    e0 = embw[u]; e1 = embw[20 + u]; e2 = embw[40 + u];
    e3 = embw[60 + u]; e4 = embw[80 + u];
  }

  // ---- init: h slots = 0, x slots = x_0 ----
  if (isU) {
    int col = 20 + u;
    zb[(col / 10) * 12 + (col % 10)] = 0.0f;
  }
  if (FIRST) {
    if (lane < 5) raw[lane] = xg[(size_t)n * 5 + lane];
    asm volatile("s_waitcnt lgkmcnt(0)" ::: "memory");
    if (isU) {
      float a = raw[0] * e0 + raw[1] * e1 + raw[2] * e2 + raw[3] * e3 + raw[4] * e4;
      zb[(u / 10) * 12 + (u % 10)] = fmaxf(a, 0.0f);
    }
  } else {
    if (isU) zb[(u / 10) * 12 + (u % 10)] = seq[(size_t)n * 20 + u];
  }
  asm volatile("s_waitcnt lgkmcnt(0)" ::: "memory");

  float c = 0.0f;
  for (int t = 0; t < T_; t++) {
    // prefetch next-step input (20-lane 80B span; consumed at step end)
    float px = 0.0f;
    if (t + 1 < T_) {
      if (FIRST) {
        if (lane < 5) px = xg[(size_t)(t + 1) * (N_ * 5) + n * 5 + lane];
      } else {
        if (isU) px = seq[(size_t)(t + 1) * (N_ * 20) + n * 20 + u];
      }
    }
    // z = [x_t | h_t] slice for this cg (broadcast, conflict-free)
    float z[10];
    {
      const float* zp = zb + cg * 12;
      float4 a4 = *reinterpret_cast<const float4*>(zp);
      float4 b4 = *reinterpret_cast<const float4*>(zp + 4);
      float2 c2 = *reinterpret_cast<const float2*>(zp + 8);
      z[0] = a4.x; z[1] = a4.y; z[2] = a4.z; z[3] = a4.w;
      z[4] = b4.x; z[5] = b4.y; z[6] = b4.z; z[7] = b4.w;
      z[8] = c2.x; z[9] = c2.y;
    }
    float acc[5];
#pragma unroll
    for (int j = 0; j < 5; j++) {
      float a = wr[j][0] * z[0];
#pragma unroll
      for (int m = 1; m < 10; m++) a += wr[j][m] * z[m];
      acc[j] = a;
    }
    // col-combine over cg (lane bits 0-1): quad_perm DPP, VALU pipe
#pragma unroll
    for (int j = 0; j < 5; j++) acc[j] += __shfl_xor(acc[j], 1, 64);
#pragma unroll
    for (int j = 0; j < 5; j++) acc[j] += __shfl_xor(acc[j], 2, 64);
    // distributed branchless activation: lane handles row rg*5+cg (+4 if cg0)
    {
      float xA = acc[0];
      if (cg == 1) xA = acc[1];
      if (cg == 2) xA = acc[2];
      if (cg == 3) xA = acc[3];
      xA += bA;
      float eA = __expf(xA * nS);
      *grA = __fdividef(mM, 1.0f + eA) + aA;
      if (cg == 0) {
        float xB = acc[4] + bB;
        float eB = __expf(xB * nS);
        *grB = __fdividef(mM, 1.0f + eB) + aA;
      }
    }
    asm volatile("s_waitcnt lgkmcnt(0)" ::: "memory");
    // state update (lanes u<20): gates already activated
    if (isU) {
      float gi = gr[u];
      float gf = gr[20 + u];
      float gg = gr[40 + u];
      float go = gr[60 + u];
      float cu = gf * c + gi * gg;
      c = cu;
      float ec = __expf(-2.0f * cu);
      float h = go * (__fdividef(2.0f, 1.0f + ec) - 1.0f);
      seq[(size_t)t * (N_ * 20) + n * 20 + u] = h;   // 80B contiguous per wave
      int col = 20 + u;
      zb[(col / 10) * 12 + (col % 10)] = h;
    }
    if (t + 1 < T_) {
      if (FIRST) {
        if (lane < 5) raw[lane] = px;
        asm volatile("s_waitcnt lgkmcnt(0) vmcnt(0)" ::: "memory");
        if (isU) {
          float a = raw[0] * e0 + raw[1] * e1 + raw[2] * e2 + raw[3] * e3 + raw[4] * e4;
          zb[(u / 10) * 12 + (u % 10)] = fmaxf(a, 0.0f);
        }
      } else {
        if (isU) zb[(u / 10) * 12 + (u % 10)] = px;
      }
    }
    asm volatile("s_waitcnt lgkmcnt(0)" ::: "memory");
  }
}

// ---------------- attention over T, one wave per element ----------------
__global__ void __launch_bounds__(256) attn_kernel(
    const float* __restrict__ seq, const float* __restrict__ w1,
    const float* __restrict__ b1v, const float* __restrict__ w2,
    const float* __restrict__ b2v, float* __restrict__ xh, float* __restrict__ xhn) {
  const int wv = threadIdx.x >> 6;
  const int t = threadIdx.x & 63;
  const int n = (blockIdx.x << 2) + wv;
  const bool act = (t < T_);
  float enc[20];
#pragma unroll
  for (int k = 0; k < 20; k++) enc[k] = 0.0f;
  if (act) {
    const float* p = seq + (t * N_ + n) * H_;
#pragma unroll
    for (int q = 0; q < 5; q++) {
      float4 v = *reinterpret_cast<const float4*>(p + 4 * q);
      enc[4 * q] = v.x; enc[4 * q + 1] = v.y; enc[4 * q + 2] = v.z; enc[4 * q + 3] = v.w;
    }
  }
  float e = -3.0e38f;
  if (act) {
    e = b2v[0];
#pragma unroll 4
    for (int k = 0; k < 64; k++) {
      float s = b1v[k];
      const float* wr = w1 + k * 20;
#pragma unroll
      for (int m = 0; m < 20; m++) s += wr[m] * enc[m];
      s = fmaxf(s, 0.0f);
      e += w2[k] * s;
    }
  }
  float mx = e;
#pragma unroll
  for (int d = 32; d; d >>= 1) mx = fmaxf(mx, __shfl_xor(mx, d, 64));
  float p_ = act ? __expf(e - mx) : 0.0f;
  float sm = p_;
#pragma unroll
  for (int d = 32; d; d >>= 1) sm += __shfl_xor(sm, d, 64);
  float w = __fdividef(p_, sm);
  float a[20];
#pragma unroll
  for (int k = 0; k < 20; k++) a[k] = enc[k] * w;
#pragma unroll
  for (int d = 1; d < 64; d <<= 1) {
#pragma unroll
    for (int k = 0; k < 20; k++) a[k] += __shfl_xor(a[k], d, 64);
  }
  if (t == 0) {
    float* op = xh + n * 20;
    float s2 = 0.0f;
#pragma unroll
    for (int k = 0; k < 20; k++) s2 += a[k] * a[k];
#pragma unroll
    for (int q = 0; q < 5; q++) {
      float4 v; v.x = a[4 * q]; v.y = a[4 * q + 1]; v.z = a[4 * q + 2]; v.w = a[4 * q + 3];
      *reinterpret_cast<float4*>(op + 4 * q) = v;
    }
    xhn[n] = sqrtf(s2);
  }
}

// ---------------- x0 norms ----------------
__global__ void __launch_bounds__(256) x0norm_kernel(const float* __restrict__ x0,
                                                     float* __restrict__ nx0,
                                                     float* __restrict__ rx0) {
  int j = blockIdx.x * 256 + threadIdx.x;
  if (j >= N0_) return;
  float s = 0.f;
#pragma unroll
  for (int k = 0; k < 20; k++) { float v = x0[j * 20 + k]; s += v * v; }
  float nv = sqrtf(s);
  nx0[j] = nv;
  rx0[j] = 1.0f / nv;
}

// ---------------- top-6 cosine, 16 lanes per row ----------------
__device__ __forceinline__ bool better_(float v1, int i1, float v2, int i2) {
  return (v1 > v2) || (v1 == v2 && i1 < i2);
}

__device__ __forceinline__ void merge6(float tv[6], int ti[6], int d) {
  float cv[12]; int ci[12];
#pragma unroll
  for (int z = 0; z < 6; z++) { cv[z] = tv[z]; ci[z] = ti[z]; }
#pragma unroll
  for (int z = 0; z < 6; z++) {
    cv[6 + z] = __shfl_xor(tv[z], d, 64);
    ci[6 + z] = __shfl_xor(ti[z], d, 64);
  }
#pragma unroll
  for (int o = 0; o < 6; o++) {
    float bv = -3.0e38f; int bi = 0x7fffffff; int bm = -1;
#pragma unroll
    for (int m = 0; m < 12; m++) {
      bool bt = better_(cv[m], ci[m], bv, bi);
      if (bt) { bv = cv[m]; bi = ci[m]; bm = m; }
    }
    tv[o] = bv; ti[o] = bi;
#pragma unroll
    for (int m = 0; m < 12; m++) if (m == bm) cv[m] = -3.0e38f;
  }
}

__global__ void __launch_bounds__(256) topk_kernel(
    const float* __restrict__ x0, const float* __restrict__ xh,
    const float* __restrict__ xhn, const float* __restrict__ nx0,
    const float* __restrict__ rx0, int* __restrict__ top5) {
  const int gt = blockIdx.x * 256 + threadIdx.x;
  const int i = gt >> 4, sub = gt & 15;
  float q[20];
  const float* qp = xh + i * 20;
#pragma unroll
  for (int z = 0; z < 5; z++) {
    float4 v = *reinterpret_cast<const float4*>(qp + 4 * z);
    q[4 * z] = v.x; q[4 * z + 1] = v.y; q[4 * z + 2] = v.z; q[4 * z + 3] = v.w;
  }
  float tv[6]; int ti[6];
#pragma unroll
  for (int z = 0; z < 6; z++) { tv[z] = -1.0e30f; ti[z] = 0x7fffffff; }
  for (int j = sub; j < N0_; j += 16) {
    const float* xr = x0 + j * 20;
    float d0 = 0.f;
#pragma unroll
    for (int k = 0; k < 20; k++) d0 += q[k] * xr[k];
    float key = d0 * rx0[j];
    if (key > tv[5]) {       // within-lane j ascending => strict > keeps stability
      tv[5] = key; ti[5] = j;
#pragma unroll
      for (int z = 5; z >= 1; z--) {
        bool sw = better_(tv[z], ti[z], tv[z - 1], ti[z - 1]);
        if (sw) {
          float fv = tv[z]; tv[z] = tv[z - 1]; tv[z - 1] = fv;
          int iv = ti[z]; ti[z] = ti[z - 1]; ti[z - 1] = iv;
        }
      }
    }
  }
  merge6(tv, ti, 1);
  merge6(tv, ti, 2);
  merge6(tv, ti, 4);
  merge6(tv, ti, 8);
  if (sub == 0) {
    const float* xr = x0 + ti[0] * 20;
    float d0 = 0.f;
#pragma unroll
    for (int k = 0; k < 20; k++) d0 += q[k] * xr[k];
    float a = (d0 / xhn[i]) / nx0[ti[0]];   // replicate ref's exact-match branch
    int base = (a == 1.0f) ? 1 : 0;
#pragma unroll
    for (int z = 0; z < 5; z++) top5[i * 5 + z] = ti[base + z];
  }
}

// ---------------- SAGE layer-1 aggregation over edge_0 ----------------
__global__ void __launch_bounds__(256) scatter_kernel(const int* __restrict__ edge,
                                                      const float* __restrict__ x0,
                                                      float* sum1, float* cnt1) {
  int e = blockIdx.x * 256 + threadIdx.x;
  if (e >= E0_) return;
  int s = edge[e], d = edge[E0_ + e];
  const float* xr = x0 + s * 20;
  float* dr = sum1 + d * 20;
#pragma unroll
  for (int k = 0; k < 20; k++) atomicAdd(dr + k, xr[k]);
  atomicAdd(cnt1 + d, 1.0f);
}

__global__ void __launch_bounds__(256) base_kernel(
    const float* __restrict__ x0, const float* __restrict__ sum1,
    const float* __restrict__ cnt1, const float* __restrict__ w1l,
    const float* __restrict__ w1r, const float* __restrict__ b1,
    float* __restrict__ obase) {
  int j = blockIdx.x * 256 + threadIdx.x;
  if (j >= N0_) return;
  float cm = fmaxf(cnt1[j], 1.0f);
  float mean[20], xv[20];
#pragma unroll
  for (int k = 0; k < 20; k++) {
    mean[k] = sum1[j * 20 + k] / cm;
    xv[k] = x0[j * 20 + k];
  }
#pragma unroll
  for (int c = 0; c < HC_; c++) {
    float a = b1[c];
#pragma unroll
    for (int k = 0; k < 20; k++) a += mean[k] * w1l[c * 20 + k];
#pragma unroll
    for (int k = 0; k < 20; k++) a += xv[k] * w1r[c * 20 + k];
    obase[j * HC_ + c] = fmaxf(a, 0.0f);
  }
}

// ---------------- SAGE layer-2 at new nodes + linear + softmax ----------------
__global__ void __launch_bounds__(256) final_kernel(
    const float* __restrict__ xh, const int* __restrict__ top5,
    const float* __restrict__ obase, const float* __restrict__ w1r,
    const float* __restrict__ b1, const float* __restrict__ w2l,
    const float* __restrict__ w2r, const float* __restrict__ b2,
    const float* __restrict__ wlin, const float* __restrict__ blin,
    float* __restrict__ out) {
  int n = blockIdx.x * 256 + threadIdx.x;
  if (n >= N_) return;
  float xq[20];
#pragma unroll
  for (int k = 0; k < 20; k++) xq[k] = xh[n * 20 + k];
  float onw[15];   // layer-1 output at this new node (mean = 0: no incoming edge_0)
#pragma unroll
  for (int c = 0; c < HC_; c++) {
    float a = b1[c];
#pragma unroll
    for (int k = 0; k < 20; k++) a += xq[k] * w1r[c * 20 + k];
    onw[c] = fmaxf(a, 0.0f);
  }
  float mean[15];
#pragma unroll
  for (int c = 0; c < HC_; c++) mean[c] = 0.0f;
#pragma unroll
  for (int z = 0; z < K_; z++) {
    int idx = top5[n * 5 + z];
#pragma unroll
    for (int c = 0; c < HC_; c++) mean[c] += obase[idx * HC_ + c];
  }
#pragma unroll
  for (int c = 0; c < HC_; c++) mean[c] = mean[c] / 5.0f;
  float lg[3];
#pragma unroll
  for (int cl = 0; cl < 3; cl++) lg[cl] = blin[cl];
#pragma unroll
  for (int dd = 0; dd < 20; dd++) {
    float v = b2[dd];
#pragma unroll
    for (int c = 0; c < HC_; c++) v += mean[c] * w2l[dd * HC_ + c] + onw[c] * w2r[dd * HC_ + c];
#pragma unroll
    for (int cl = 0; cl < 3; cl++) lg[cl] += v * wlin[cl * 20 + dd];
  }
  float m = fmaxf(lg[0], fmaxf(lg[1], lg[2]));
  float e0 = expf(lg[0] - m), e1 = expf(lg[1] - m), e2 = expf(lg[2] - m);
  float s = e0 + e1 + e2;
  out[n * 3 + 0] = e0 / s;
  out[n * 3 + 1] = e1 / s;
  out[n * 3 + 2] = e2 / s;
}

extern "C" void kernel_launch(void* const* d_in, const int* in_sizes, int n_in,
                              void* d_out, int out_size, void* d_ws, size_t ws_size,
                              hipStream_t stream) {
  const float* x    = (const float*)d_in[0];
  const float* x0   = (const float*)d_in[1];
  const float* embw = (const float*)d_in[2];
  const float* Wih  = (const float*)d_in[3];
  const float* Whh  = (const float*)d_in[4];
  const float* bih  = (const float*)d_in[5];
  const float* bhh  = (const float*)d_in[6];
  const float* aw1  = (const float*)d_in[7];
  const float* ab1  = (const float*)d_in[8];
  const float* aw2  = (const float*)d_in[9];
  const float* ab2  = (const float*)d_in[10];
  const float* w1l  = (const float*)d_in[11];
  const float* w1r  = (const float*)d_in[12];
  const float* b1   = (const float*)d_in[13];
  const float* w2l  = (const float*)d_in[14];
  const float* w2r  = (const float*)d_in[15];
  const float* b2   = (const float*)d_in[16];
  const float* wlin = (const float*)d_in[17];
  const float* blin = (const float*)d_in[18];
  const int* edge0  = (const int*)d_in[19];

  float* ws    = (float*)d_ws;
  float* seq   = ws + OFF_SEQ;
  float* xh    = ws + OFF_XH;
  float* xhn   = ws + OFF_XHN;
  float* nx0   = ws + OFF_NX0;
  float* rx0   = ws + OFF_RX0;
  int*   top5  = (int*)(ws + OFF_TOP5);
  float* sum1  = ws + OFF_SUM1;
  float* cnt1  = ws + OFF_CNT1;
  float* obase = ws + OFF_OBASE;
  float* out   = (float*)d_out;

  hipMemsetAsync(sum1, 0, (size_t)(N0_ * H_ + N0_) * sizeof(float), stream);
  lstm_wpe_kernel<true><<<N_ / 4, 256, 0, stream>>>(x, embw, Wih, Whh, bih, bhh, seq);
  for (int l = 1; l < 4; l++)
    lstm_wpe_kernel<false><<<N_ / 4, 256, 0, stream>>>(x, embw, Wih + l * 1600,
                                                       Whh + l * 1600, bih + l * 80,
                                                       bhh + l * 80, seq);
  attn_kernel<<<N_ / 4, 256, 0, stream>>>(seq, aw1, ab1, aw2, ab2, xh, xhn);
  x0norm_kernel<<<(N0_ + 255) / 256, 256, 0, stream>>>(x0, nx0, rx0);
  topk_kernel<<<(N_ * 16) / 256, 256, 0, stream>>>(x0, xh, xhn, nx0, rx0, top5);
  scatter_kernel<<<(E0_ + 255) / 256, 256, 0, stream>>>(edge0, x0, sum1, cnt1);
  base_kernel<<<(N0_ + 255) / 256, 256, 0, stream>>>(x0, sum1, cnt1, w1l, w1r, b1, obase);
  final_kernel<<<N_ / 256, 256, 0, stream>>>(xh, top5, obase, w1r, b1, w2l, w2r, b2,
                                             wlin, blin, out);
}

// Round 13
// 1123.022 us; speedup vs baseline: 1.3664x; 1.3664x over previous
//
#include <hip/hip_runtime.h>
#include <math.h>

#define T_ 60
#define N_ 16384
#define C_ 5
#define H_ 20
#define G_ 80
#define HC_ 15
#define N0_ 3190
#define E0_ 31900
#define K_ 5

// workspace layout (float offsets)
#define OFF_SEQ   0
#define OFF_XH    (T_*N_*H_)            // 19,660,800
#define OFF_XHN   (OFF_XH + N_*H_)
#define OFF_NX0   (OFF_XHN + N_)
#define OFF_RX0   (OFF_NX0 + N0_)
#define OFF_TOP5  (OFF_RX0 + N0_)       // int[ N_*K_ ]
#define OFF_SUM1  (OFF_TOP5 + N_*K_)
#define OFF_CNT1  (OFF_SUM1 + N0_*H_)
#define OFF_OBASE (OFF_CNT1 + N0_)

__device__ __forceinline__ float sigf(float x) {
  return __fdividef(1.0f, 1.0f + __expf(-x));
}
__device__ __forceinline__ float tanhf_fast(float x) {
  float xc = fminf(fmaxf(x, -44.0f), 44.0f);
  float e = __expf(2.0f * xc);
  return __fdividef(e - 1.0f, e + 1.0f);
}

// ============================================================================
// LSTM layer "wpe2": WAVE-PER-2-ELEMENTS. Round-11 (1 el/wave) was VALU~80%
// with the 15-DS/step weight stream and wave-wide u-phase as per-WAVE costs.
// Round-12's distributed activation regressed (scattered-write conflicts +
// extra LDS round trip) - reverted to v1 u-phase. Here those per-wave costs
// amortize over 2 elements:
//  - lane (rg,cg) computes acc0/acc1 for elements n0=(blk*8+2w), n1=n0+1
//    from two z-buffers (100 fmacs/step/lane).
//  - combine: shfl_xor(1)+shfl_xor(2) per element (quad_perm DPP).
//  - cg==0 writes RAW gates to gr0/gr1 (stride-5 pattern, conflict-free x2).
//  - u-phase: lanes 0-19 el0, lanes 32-51 el1 (24 idle vs 44) - activation
//    chains serve both elements in parallel, same serial depth.
//  - stores: el0 span + el1 span are contiguous (n1=n0+1) -> 160B/wave dense.
//  - launch_bounds stays (256,2): rounds 6/10 proved raising min-occupancy
//    caps VGPR below need -> scratch spill. DO NOT raise.
// ============================================================================

#define LWV 272  // per-wave floats: zb0[48] zb1@48[48] gr0@96[80] gr1@176[80] raw@256[10]

template <bool FIRST>
__global__ void __launch_bounds__(256, 2) lstm_wpe2_kernel(
    const float* __restrict__ xg,      // [T, N, 5] raw codes (FIRST only)
    const float* __restrict__ embw,    // [5, 20]              (FIRST only)
    const float* __restrict__ Wih,     // [80, 20] this layer
    const float* __restrict__ Whh,     // [80, 20]
    const float* __restrict__ bih,     // [80]
    const float* __restrict__ bhh,     // [80]
    float* __restrict__ seq) {         // in (!FIRST) and out: [T, N, 20]
  __shared__ __align__(16) float wst[3200];     // staged [80][40]
  __shared__ __align__(16) float wsh[4 * LWV];  // per-wave regions
  const int tid = threadIdx.x;

  for (int i = tid; i < 3200; i += 256) {
    int r = i / 40, col = i % 40;
    wst[i] = (col < 20) ? Wih[r * 20 + col] : Whh[r * 20 + (col - 20)];
  }
  __syncthreads();

  const int lane = tid & 63;
  const int w = tid >> 6;
  const int rg = lane >> 2;            // row group: rows rg*5..rg*5+4
  const int cg = lane & 3;             // col group: cols cg*10..cg*10+9
  const int n0 = (blockIdx.x << 3) + (w << 1);
  const int n1 = n0 + 1;
  float* zb0 = &wsh[w * LWV];          // el0 z: [4 slots][12]
  float* zb1 = zb0 + 48;               // el1 z
  float* gr0 = zb0 + 96;               // el0 raw gates [80]
  float* gr1 = zb0 + 176;              // el1 raw gates [80]
  float* raw = zb0 + 256;              // FIRST codes: el0 @0..4, el1 @5..9

  // ---- weight registers ----
  float wr[5][10];
  {
    const float* bp = &wst[(rg * 5) * 40 + cg * 10];
#pragma unroll
    for (int j = 0; j < 5; j++)
#pragma unroll
      for (int m = 0; m < 10; m++) wr[j][m] = bp[j * 40 + m];
  }
#pragma unroll
  for (int j = 0; j < 5; j++)
#pragma unroll
    for (int m = 0; m < 10; m++) asm volatile("" : "+v"(wr[j][m]));

  // ---- u-lane roles: lanes 0-19 -> el0, lanes 32-51 -> el1 ----
  const bool isU0 = (lane < 20);
  const bool isU1 = (lane >= 32 && lane < 52);
  const bool isU = isU0 || isU1;
  const int u = isU0 ? lane : (isU1 ? (lane - 32) : 0);
  const int myn = isU1 ? n1 : n0;
  float* myzb = isU1 ? zb1 : zb0;
  const float* mygr = isU1 ? gr1 : gr0;
  const float* myraw = isU1 ? (raw + 5) : raw;

  const float bi = bih[u] + bhh[u];
  const float bf = bih[20 + u] + bhh[20 + u];
  const float bg = bih[40 + u] + bhh[40 + u];
  const float bo = bih[60 + u] + bhh[60 + u];
  float e0 = 0, e1 = 0, e2 = 0, e3 = 0, e4 = 0;
  if (FIRST) {
    e0 = embw[u]; e1 = embw[20 + u]; e2 = embw[40 + u];
    e3 = embw[60 + u]; e4 = embw[80 + u];
  }

  // ---- init: h slots = 0, x slots = x_0 ----
  if (isU) {
    int col = 20 + u;
    myzb[(col / 10) * 12 + (col % 10)] = 0.0f;
  }
  if (FIRST) {
    if (lane < 5) raw[lane] = xg[(size_t)n0 * 5 + lane];
    if (lane >= 32 && lane < 37) raw[5 + (lane - 32)] = xg[(size_t)n1 * 5 + (lane - 32)];
    asm volatile("s_waitcnt lgkmcnt(0)" ::: "memory");
    if (isU) {
      float a = myraw[0] * e0 + myraw[1] * e1 + myraw[2] * e2 + myraw[3] * e3
              + myraw[4] * e4;
      myzb[(u / 10) * 12 + (u % 10)] = fmaxf(a, 0.0f);
    }
  } else {
    if (isU) myzb[(u / 10) * 12 + (u % 10)] = seq[(size_t)myn * 20 + u];
  }
  asm volatile("s_waitcnt lgkmcnt(0)" ::: "memory");

  float c = 0.0f;
  for (int t = 0; t < T_; t++) {
    // prefetch next-step input
    float px = 0.0f;
    if (t + 1 < T_) {
      if (FIRST) {
        if (lane < 5) px = xg[(size_t)(t + 1) * (N_ * 5) + n0 * 5 + lane];
        if (lane >= 32 && lane < 37)
          px = xg[(size_t)(t + 1) * (N_ * 5) + n1 * 5 + (lane - 32)];
      } else {
        if (isU) px = seq[(size_t)(t + 1) * (N_ * 20) + myn * 20 + u];
      }
    }
    // z slices for this cg (broadcast, conflict-free / free 2-way)
    float z0[10], z1[10];
    {
      const float* zp = zb0 + cg * 12;
      float4 a4 = *reinterpret_cast<const float4*>(zp);
      float4 b4 = *reinterpret_cast<const float4*>(zp + 4);
      float2 c2 = *reinterpret_cast<const float2*>(zp + 8);
      z0[0] = a4.x; z0[1] = a4.y; z0[2] = a4.z; z0[3] = a4.w;
      z0[4] = b4.x; z0[5] = b4.y; z0[6] = b4.z; z0[7] = b4.w;
      z0[8] = c2.x; z0[9] = c2.y;
      const float* zq = zb1 + cg * 12;
      float4 d4 = *reinterpret_cast<const float4*>(zq);
      float4 e4_ = *reinterpret_cast<const float4*>(zq + 4);
      float2 f2 = *reinterpret_cast<const float2*>(zq + 8);
      z1[0] = d4.x; z1[1] = d4.y; z1[2] = d4.z; z1[3] = d4.w;
      z1[4] = e4_.x; z1[5] = e4_.y; z1[6] = e4_.z; z1[7] = e4_.w;
      z1[8] = f2.x; z1[9] = f2.y;
    }
    float acc0[5], acc1[5];
#pragma unroll
    for (int j = 0; j < 5; j++) {
      float a0 = wr[j][0] * z0[0];
      float a1 = wr[j][0] * z1[0];
#pragma unroll
      for (int m = 1; m < 10; m++) {
        a0 += wr[j][m] * z0[m];
        a1 += wr[j][m] * z1[m];
      }
      acc0[j] = a0; acc1[j] = a1;
    }
    // col-combine over cg: quad_perm DPP
#pragma unroll
    for (int j = 0; j < 5; j++) { acc0[j] += __shfl_xor(acc0[j], 1, 64);
                                  acc1[j] += __shfl_xor(acc1[j], 1, 64); }
#pragma unroll
    for (int j = 0; j < 5; j++) { acc0[j] += __shfl_xor(acc0[j], 2, 64);
                                  acc1[j] += __shfl_xor(acc1[j], 2, 64); }
    if (cg == 0) {
#pragma unroll
      for (int j = 0; j < 5; j++) { gr0[rg * 5 + j] = acc0[j];
                                    gr1[rg * 5 + j] = acc1[j]; }
    }
    asm volatile("s_waitcnt lgkmcnt(0)" ::: "memory");
    // gates / state / IO
    if (isU) {
      float gi = mygr[u] + bi;
      float gf = mygr[20 + u] + bf;
      float gg = mygr[40 + u] + bg;
      float go = mygr[60 + u] + bo;
      float cu = sigf(gf) * c + sigf(gi) * tanhf_fast(gg);
      c = cu;
      float h = sigf(go) * tanhf_fast(cu);
      seq[(size_t)t * (N_ * 20) + myn * 20 + u] = h;   // dense 160B/wave
      int col = 20 + u;
      myzb[(col / 10) * 12 + (col % 10)] = h;
    }
    if (t + 1 < T_) {
      if (FIRST) {
        if (lane < 5) raw[lane] = px;
        if (lane >= 32 && lane < 37) raw[5 + (lane - 32)] = px;
        asm volatile("s_waitcnt lgkmcnt(0) vmcnt(0)" ::: "memory");
        if (isU) {
          float a = myraw[0] * e0 + myraw[1] * e1 + myraw[2] * e2 + myraw[3] * e3
                  + myraw[4] * e4;
          myzb[(u / 10) * 12 + (u % 10)] = fmaxf(a, 0.0f);
        }
      } else {
        if (isU) myzb[(u / 10) * 12 + (u % 10)] = px;
      }
    }
    asm volatile("s_waitcnt lgkmcnt(0)" ::: "memory");
  }
}

// ---------------- attention over T, one wave per element ----------------
__global__ void __launch_bounds__(256) attn_kernel(
    const float* __restrict__ seq, const float* __restrict__ w1,
    const float* __restrict__ b1v, const float* __restrict__ w2,
    const float* __restrict__ b2v, float* __restrict__ xh, float* __restrict__ xhn) {
  const int wv = threadIdx.x >> 6;
  const int t = threadIdx.x & 63;
  const int n = (blockIdx.x << 2) + wv;
  const bool act = (t < T_);
  float enc[20];
#pragma unroll
  for (int k = 0; k < 20; k++) enc[k] = 0.0f;
  if (act) {
    const float* p = seq + (t * N_ + n) * H_;
#pragma unroll
    for (int q = 0; q < 5; q++) {
      float4 v = *reinterpret_cast<const float4*>(p + 4 * q);
      enc[4 * q] = v.x; enc[4 * q + 1] = v.y; enc[4 * q + 2] = v.z; enc[4 * q + 3] = v.w;
    }
  }
  float e = -3.0e38f;
  if (act) {
    e = b2v[0];
#pragma unroll 4
    for (int k = 0; k < 64; k++) {
      float s = b1v[k];
      const float* wr = w1 + k * 20;
#pragma unroll
      for (int m = 0; m < 20; m++) s += wr[m] * enc[m];
      s = fmaxf(s, 0.0f);
      e += w2[k] * s;
    }
  }
  float mx = e;
#pragma unroll
  for (int d = 32; d; d >>= 1) mx = fmaxf(mx, __shfl_xor(mx, d, 64));
  float p_ = act ? __expf(e - mx) : 0.0f;
  float sm = p_;
#pragma unroll
  for (int d = 32; d; d >>= 1) sm += __shfl_xor(sm, d, 64);
  float w = __fdividef(p_, sm);
  float a[20];
#pragma unroll
  for (int k = 0; k < 20; k++) a[k] = enc[k] * w;
#pragma unroll
  for (int d = 1; d < 64; d <<= 1) {
#pragma unroll
    for (int k = 0; k < 20; k++) a[k] += __shfl_xor(a[k], d, 64);
  }
  if (t == 0) {
    float* op = xh + n * 20;
    float s2 = 0.0f;
#pragma unroll
    for (int k = 0; k < 20; k++) s2 += a[k] * a[k];
#pragma unroll
    for (int q = 0; q < 5; q++) {
      float4 v; v.x = a[4 * q]; v.y = a[4 * q + 1]; v.z = a[4 * q + 2]; v.w = a[4 * q + 3];
      *reinterpret_cast<float4*>(op + 4 * q) = v;
    }
    xhn[n] = sqrtf(s2);
  }
}

// ---------------- x0 norms ----------------
__global__ void __launch_bounds__(256) x0norm_kernel(const float* __restrict__ x0,
                                                     float* __restrict__ nx0,
                                                     float* __restrict__ rx0) {
  int j = blockIdx.x * 256 + threadIdx.x;
  if (j >= N0_) return;
  float s = 0.f;
#pragma unroll
  for (int k = 0; k < 20; k++) { float v = x0[j * 20 + k]; s += v * v; }
  float nv = sqrtf(s);
  nx0[j] = nv;
  rx0[j] = 1.0f / nv;
}

// ---------------- top-6 cosine, 16 lanes per row ----------------
__device__ __forceinline__ bool better_(float v1, int i1, float v2, int i2) {
  return (v1 > v2) || (v1 == v2 && i1 < i2);
}

__device__ __forceinline__ void merge6(float tv[6], int ti[6], int d) {
  float cv[12]; int ci[12];
#pragma unroll
  for (int z = 0; z < 6; z++) { cv[z] = tv[z]; ci[z] = ti[z]; }
#pragma unroll
  for (int z = 0; z < 6; z++) {
    cv[6 + z] = __shfl_xor(tv[z], d, 64);
    ci[6 + z] = __shfl_xor(ti[z], d, 64);
  }
#pragma unroll
  for (int o = 0; o < 6; o++) {
    float bv = -3.0e38f; int bi = 0x7fffffff; int bm = -1;
#pragma unroll
    for (int m = 0; m < 12; m++) {
      bool bt = better_(cv[m], ci[m], bv, bi);
      if (bt) { bv = cv[m]; bi = ci[m]; bm = m; }
    }
    tv[o] = bv; ti[o] = bi;
#pragma unroll
    for (int m = 0; m < 12; m++) if (m == bm) cv[m] = -3.0e38f;
  }
}

__global__ void __launch_bounds__(256) topk_kernel(
    const float* __restrict__ x0, const float* __restrict__ xh,
    const float* __restrict__ xhn, const float* __restrict__ nx0,
    const float* __restrict__ rx0, int* __restrict__ top5) {
  const int gt = blockIdx.x * 256 + threadIdx.x;
  const int i = gt >> 4, sub = gt & 15;
  float q[20];
  const float* qp = xh + i * 20;
#pragma unroll
  for (int z = 0; z < 5; z++) {
    float4 v = *reinterpret_cast<const float4*>(qp + 4 * z);
    q[4 * z] = v.x; q[4 * z + 1] = v.y; q[4 * z + 2] = v.z; q[4 * z + 3] = v.w;
  }
  float tv[6]; int ti[6];
#pragma unroll
  for (int z = 0; z < 6; z++) { tv[z] = -1.0e30f; ti[z] = 0x7fffffff; }
  for (int j = sub; j < N0_; j += 16) {
    const float* xr = x0 + j * 20;
    float d0 = 0.f;
#pragma unroll
    for (int k = 0; k < 20; k++) d0 += q[k] * xr[k];
    float key = d0 * rx0[j];
    if (key > tv[5]) {       // within-lane j ascending => strict > keeps stability
      tv[5] = key; ti[5] = j;
#pragma unroll
      for (int z = 5; z >= 1; z--) {
        bool sw = better_(tv[z], ti[z], tv[z - 1], ti[z - 1]);
        if (sw) {
          float fv = tv[z]; tv[z] = tv[z - 1]; tv[z - 1] = fv;
          int iv = ti[z]; ti[z] = ti[z - 1]; ti[z - 1] = iv;
        }
      }
    }
  }
  merge6(tv, ti, 1);
  merge6(tv, ti, 2);
  merge6(tv, ti, 4);
  merge6(tv, ti, 8);
  if (sub == 0) {
    const float* xr = x0 + ti[0] * 20;
    float d0 = 0.f;
#pragma unroll
    for (int k = 0; k < 20; k++) d0 += q[k] * xr[k];
    float a = (d0 / xhn[i]) / nx0[ti[0]];   // replicate ref's exact-match branch
    int base = (a == 1.0f) ? 1 : 0;
#pragma unroll
    for (int z = 0; z < 5; z++) top5[i * 5 + z] = ti[base + z];
  }
}

// ---------------- SAGE layer-1 aggregation over edge_0 ----------------
__global__ void __launch_bounds__(256) scatter_kernel(const int* __restrict__ edge,
                                                      const float* __restrict__ x0,
                                                      float* sum1, float* cnt1) {
  int e = blockIdx.x * 256 + threadIdx.x;
  if (e >= E0_) return;
  int s = edge[e], d = edge[E0_ + e];
  const float* xr = x0 + s * 20;
  float* dr = sum1 + d * 20;
#pragma unroll
  for (int k = 0; k < 20; k++) atomicAdd(dr + k, xr[k]);
  atomicAdd(cnt1 + d, 1.0f);
}

__global__ void __launch_bounds__(256) base_kernel(
    const float* __restrict__ x0, const float* __restrict__ sum1,
    const float* __restrict__ cnt1, const float* __restrict__ w1l,
    const float* __restrict__ w1r, const float* __restrict__ b1,
    float* __restrict__ obase) {
  int j = blockIdx.x * 256 + threadIdx.x;
  if (j >= N0_) return;
  float cm = fmaxf(cnt1[j], 1.0f);
  float mean[20], xv[20];
#pragma unroll
  for (int k = 0; k < 20; k++) {
    mean[k] = sum1[j * 20 + k] / cm;
    xv[k] = x0[j * 20 + k];
  }
#pragma unroll
  for (int c = 0; c < HC_; c++) {
    float a = b1[c];
#pragma unroll
    for (int k = 0; k < 20; k++) a += mean[k] * w1l[c * 20 + k];
#pragma unroll
    for (int k = 0; k < 20; k++) a += xv[k] * w1r[c * 20 + k];
    obase[j * HC_ + c] = fmaxf(a, 0.0f);
  }
}

// ---------------- SAGE layer-2 at new nodes + linear + softmax ----------------
__global__ void __launch_bounds__(256) final_kernel(
    const float* __restrict__ xh, const int* __restrict__ top5,
    const float* __restrict__ obase, const float* __restrict__ w1r,
    const float* __restrict__ b1, const float* __restrict__ w2l,
    const float* __restrict__ w2r, const float* __restrict__ b2,
    const float* __restrict__ wlin, const float* __restrict__ blin,
    float* __restrict__ out) {
  int n = blockIdx.x * 256 + threadIdx.x;
  if (n >= N_) return;
  float xq[20];
#pragma unroll
  for (int k = 0; k < 20; k++) xq[k] = xh[n * 20 + k];
  float onw[15];   // layer-1 output at this new node (mean = 0: no incoming edge_0)
#pragma unroll
  for (int c = 0; c < HC_; c++) {
    float a = b1[c];
#pragma unroll
    for (int k = 0; k < 20; k++) a += xq[k] * w1r[c * 20 + k];
    onw[c] = fmaxf(a, 0.0f);
  }
  float mean[15];
#pragma unroll
  for (int c = 0; c < HC_; c++) mean[c] = 0.0f;
#pragma unroll
  for (int z = 0; z < K_; z++) {
    int idx = top5[n * 5 + z];
#pragma unroll
    for (int c = 0; c < HC_; c++) mean[c] += obase[idx * HC_ + c];
  }
#pragma unroll
  for (int c = 0; c < HC_; c++) mean[c] = mean[c] / 5.0f;
  float lg[3];
#pragma unroll
  for (int cl = 0; cl < 3; cl++) lg[cl] = blin[cl];
#pragma unroll
  for (int dd = 0; dd < 20; dd++) {
    float v = b2[dd];
#pragma unroll
    for (int c = 0; c < HC_; c++) v += mean[c] * w2l[dd * HC_ + c] + onw[c] * w2r[dd * HC_ + c];
#pragma unroll
    for (int cl = 0; cl < 3; cl++) lg[cl] += v * wlin[cl * 20 + dd];
  }
  float m = fmaxf(lg[0], fmaxf(lg[1], lg[2]));
  float e0 = expf(lg[0] - m), e1 = expf(lg[1] - m), e2 = expf(lg[2] - m);
  float s = e0 + e1 + e2;
  out[n * 3 + 0] = e0 / s;
  out[n * 3 + 1] = e1 / s;
  out[n * 3 + 2] = e2 / s;
}

extern "C" void kernel_launch(void* const* d_in, const int* in_sizes, int n_in,
                              void* d_out, int out_size, void* d_ws, size_t ws_size,
                              hipStream_t stream) {
  const float* x    = (const float*)d_in[0];
  const float* x0   = (const float*)d_in[1];
  const float* embw = (const float*)d_in[2];
  const float* Wih  = (const float*)d_in[3];
  const float* Whh  = (const float*)d_in[4];
  const float* bih  = (const float*)d_in[5];
  const float* bhh  = (const float*)d_in[6];
  const float* aw1  = (const float*)d_in[7];
  const float* ab1  = (const float*)d_in[8];
  const float* aw2  = (const float*)d_in[9];
  const float* ab2  = (const float*)d_in[10];
  const float* w1l  = (const float*)d_in[11];
  const float* w1r  = (const float*)d_in[12];
  const float* b1   = (const float*)d_in[13];
  const float* w2l  = (const float*)d_in[14];
  const float* w2r  = (const float*)d_in[15];
  const float* b2   = (const float*)d_in[16];
  const float* wlin = (const float*)d_in[17];
  const float* blin = (const float*)d_in[18];
  const int* edge0  = (const int*)d_in[19];

  float* ws    = (float*)d_ws;
  float* seq   = ws + OFF_SEQ;
  float* xh    = ws + OFF_XH;
  float* xhn   = ws + OFF_XHN;
  float* nx0   = ws + OFF_NX0;
  float* rx0   = ws + OFF_RX0;
  int*   top5  = (int*)(ws + OFF_TOP5);
  float* sum1  = ws + OFF_SUM1;
  float* cnt1  = ws + OFF_CNT1;
  float* obase = ws + OFF_OBASE;
  float* out   = (float*)d_out;

  hipMemsetAsync(sum1, 0, (size_t)(N0_ * H_ + N0_) * sizeof(float), stream);
  lstm_wpe2_kernel<true><<<N_ / 8, 256, 0, stream>>>(x, embw, Wih, Whh, bih, bhh, seq);
  for (int l = 1; l < 4; l++)
    lstm_wpe2_kernel<false><<<N_ / 8, 256, 0, stream>>>(x, embw, Wih + l * 1600,
                                                        Whh + l * 1600, bih + l * 80,
                                                        bhh + l * 80, seq);
  attn_kernel<<<N_ / 4, 256, 0, stream>>>(seq, aw1, ab1, aw2, ab2, xh, xhn);
  x0norm_kernel<<<(N0_ + 255) / 256, 256, 0, stream>>>(x0, nx0, rx0);
  topk_kernel<<<(N_ * 16) / 256, 256, 0, stream>>>(x0, xh, xhn, nx0, rx0, top5);
  scatter_kernel<<<(E0_ + 255) / 256, 256, 0, stream>>>(edge0, x0, sum1, cnt1);
  base_kernel<<<(N0_ + 255) / 256, 256, 0, stream>>>(x0, sum1, cnt1, w1l, w1r, b1, obase);
  final_kernel<<<N_ / 256, 256, 0, stream>>>(xh, top5, obase, w1r, b1, w2l, w2r, b2,
                                             wlin, blin, out);
}

// Round 14
// 1097.170 us; speedup vs baseline: 1.3986x; 1.0236x over previous
//
#include <hip/hip_runtime.h>
#include <math.h>

#define T_ 60
#define N_ 16384
#define C_ 5
#define H_ 20
#define G_ 80
#define HC_ 15
#define N0_ 3190
#define E0_ 31900
#define K_ 5

// workspace layout (float offsets)
#define OFF_SEQ   0
#define OFF_XH    (T_*N_*H_)            // 19,660,800
#define OFF_XHN   (OFF_XH + N_*H_)
#define OFF_NX0   (OFF_XHN + N_)
#define OFF_RX0   (OFF_NX0 + N0_)
#define OFF_TOP5  (OFF_RX0 + N0_)       // int[ N_*K_ ]
#define OFF_SUM1  (OFF_TOP5 + N_*K_)
#define OFF_CNT1  (OFF_SUM1 + N0_*H_)
#define OFF_OBASE (OFF_CNT1 + N0_)

__device__ __forceinline__ float sigf(float x) {
  return __fdividef(1.0f, 1.0f + __expf(-x));
}
__device__ __forceinline__ float tanhf_fast(float x) {
  float xc = fminf(fmaxf(x, -44.0f), 44.0f);
  float e = __expf(2.0f * xc);
  return __fdividef(e - 1.0f, e + 1.0f);
}

// ============================================================================
// LSTM layer "wpe2" v2: WAVE-PER-2-ELEMENTS, NO LDS WEIGHT BUFFER.
// Round-13 discovery: occupancy == floor(64KB / LDS_Block_Size) blocks/CU
// (r11: 15.4KB->4 blocks->51%; r13: 17.4KB->3 blocks->39%). The 12.8KB wst
// staging array (used once) was capping residency. Changes:
//  - weights loaded DIRECTLY from global into regs (one-time, L2-resident
//    after block 0); no wst, no __syncthreads -> fully barrier-free kernel.
//  - LDS = per-wave wsh only (~4.4KB) -> 8 blocks/CU (grid-bound), and the
//    allocator must keep weights in VGPRs (no LDS copy to re-read).
//  - everything else identical to round-13 wpe2 (verified absmax 0.0).
//  - launch_bounds stays (256,2): rounds 6/10 proved raising min-occupancy
//    caps VGPR below need -> scratch spill. DO NOT raise.
// ============================================================================

#define LWV 272  // per-wave floats: zb0[48] zb1@48[48] gr0@96[80] gr1@176[80] raw@256[10]

template <bool FIRST>
__global__ void __launch_bounds__(256, 2) lstm_wpe2_kernel(
    const float* __restrict__ xg,      // [T, N, 5] raw codes (FIRST only)
    const float* __restrict__ embw,    // [5, 20]              (FIRST only)
    const float* __restrict__ Wih,     // [80, 20] this layer
    const float* __restrict__ Whh,     // [80, 20]
    const float* __restrict__ bih,     // [80]
    const float* __restrict__ bhh,     // [80]
    float* __restrict__ seq) {         // in (!FIRST) and out: [T, N, 20]
  __shared__ __align__(16) float wsh[4 * LWV];  // per-wave regions only
  const int tid = threadIdx.x;

  const int lane = tid & 63;
  const int w = tid >> 6;
  const int rg = lane >> 2;            // row group: rows rg*5..rg*5+4
  const int cg = lane & 3;             // col group: cols cg*10..cg*10+9
  const int n0 = (blockIdx.x << 3) + (w << 1);
  const int n1 = n0 + 1;
  float* zb0 = &wsh[w * LWV];          // el0 z: [4 slots][12]
  float* zb1 = zb0 + 48;               // el1 z
  float* gr0 = zb0 + 96;               // el0 raw gates [80]
  float* gr1 = zb0 + 176;              // el1 raw gates [80]
  float* raw = zb0 + 256;              // FIRST codes: el0 @0..4, el1 @5..9

  // ---- weight registers: direct global load (one-time; L2-resident) ----
  float wr[5][10];
  {
    const float* wbase = (cg < 2) ? (Wih + (rg * 5) * 20 + cg * 10)
                                  : (Whh + (rg * 5) * 20 + (cg - 2) * 10);
#pragma unroll
    for (int j = 0; j < 5; j++)
#pragma unroll
      for (int m = 0; m < 10; m++) wr[j][m] = wbase[j * 20 + m];
  }
#pragma unroll
  for (int j = 0; j < 5; j++)
#pragma unroll
    for (int m = 0; m < 10; m++) asm volatile("" : "+v"(wr[j][m]));

  // ---- u-lane roles: lanes 0-19 -> el0, lanes 32-51 -> el1 ----
  const bool isU0 = (lane < 20);
  const bool isU1 = (lane >= 32 && lane < 52);
  const bool isU = isU0 || isU1;
  const int u = isU0 ? lane : (isU1 ? (lane - 32) : 0);
  const int myn = isU1 ? n1 : n0;
  float* myzb = isU1 ? zb1 : zb0;
  const float* mygr = isU1 ? gr1 : gr0;
  const float* myraw = isU1 ? (raw + 5) : raw;

  const float bi = bih[u] + bhh[u];
  const float bf = bih[20 + u] + bhh[20 + u];
  const float bg = bih[40 + u] + bhh[40 + u];
  const float bo = bih[60 + u] + bhh[60 + u];
  float e0 = 0, e1 = 0, e2 = 0, e3 = 0, e4 = 0;
  if (FIRST) {
    e0 = embw[u]; e1 = embw[20 + u]; e2 = embw[40 + u];
    e3 = embw[60 + u]; e4 = embw[80 + u];
  }

  // ---- init: h slots = 0, x slots = x_0 ----
  if (isU) {
    int col = 20 + u;
    myzb[(col / 10) * 12 + (col % 10)] = 0.0f;
  }
  if (FIRST) {
    if (lane < 5) raw[lane] = xg[(size_t)n0 * 5 + lane];
    if (lane >= 32 && lane < 37) raw[5 + (lane - 32)] = xg[(size_t)n1 * 5 + (lane - 32)];
    asm volatile("s_waitcnt lgkmcnt(0)" ::: "memory");
    if (isU) {
      float a = myraw[0] * e0 + myraw[1] * e1 + myraw[2] * e2 + myraw[3] * e3
              + myraw[4] * e4;
      myzb[(u / 10) * 12 + (u % 10)] = fmaxf(a, 0.0f);
    }
  } else {
    if (isU) myzb[(u / 10) * 12 + (u % 10)] = seq[(size_t)myn * 20 + u];
  }
  asm volatile("s_waitcnt lgkmcnt(0)" ::: "memory");

  float c = 0.0f;
  for (int t = 0; t < T_; t++) {
    // prefetch next-step input
    float px = 0.0f;
    if (t + 1 < T_) {
      if (FIRST) {
        if (lane < 5) px = xg[(size_t)(t + 1) * (N_ * 5) + n0 * 5 + lane];
        if (lane >= 32 && lane < 37)
          px = xg[(size_t)(t + 1) * (N_ * 5) + n1 * 5 + (lane - 32)];
      } else {
        if (isU) px = seq[(size_t)(t + 1) * (N_ * 20) + myn * 20 + u];
      }
    }
    // z slices for this cg (broadcast, conflict-free / free 2-way)
    float z0[10], z1[10];
    {
      const float* zp = zb0 + cg * 12;
      float4 a4 = *reinterpret_cast<const float4*>(zp);
      float4 b4 = *reinterpret_cast<const float4*>(zp + 4);
      float2 c2 = *reinterpret_cast<const float2*>(zp + 8);
      z0[0] = a4.x; z0[1] = a4.y; z0[2] = a4.z; z0[3] = a4.w;
      z0[4] = b4.x; z0[5] = b4.y; z0[6] = b4.z; z0[7] = b4.w;
      z0[8] = c2.x; z0[9] = c2.y;
      const float* zq = zb1 + cg * 12;
      float4 d4 = *reinterpret_cast<const float4*>(zq);
      float4 e4_ = *reinterpret_cast<const float4*>(zq + 4);
      float2 f2 = *reinterpret_cast<const float2*>(zq + 8);
      z1[0] = d4.x; z1[1] = d4.y; z1[2] = d4.z; z1[3] = d4.w;
      z1[4] = e4_.x; z1[5] = e4_.y; z1[6] = e4_.z; z1[7] = e4_.w;
      z1[8] = f2.x; z1[9] = f2.y;
    }
    float acc0[5], acc1[5];
#pragma unroll
    for (int j = 0; j < 5; j++) {
      float a0 = wr[j][0] * z0[0];
      float a1 = wr[j][0] * z1[0];
#pragma unroll
      for (int m = 1; m < 10; m++) {
        a0 += wr[j][m] * z0[m];
        a1 += wr[j][m] * z1[m];
      }
      acc0[j] = a0; acc1[j] = a1;
    }
    // col-combine over cg: quad_perm DPP
#pragma unroll
    for (int j = 0; j < 5; j++) { acc0[j] += __shfl_xor(acc0[j], 1, 64);
                                  acc1[j] += __shfl_xor(acc1[j], 1, 64); }
#pragma unroll
    for (int j = 0; j < 5; j++) { acc0[j] += __shfl_xor(acc0[j], 2, 64);
                                  acc1[j] += __shfl_xor(acc1[j], 2, 64); }
    if (cg == 0) {
#pragma unroll
      for (int j = 0; j < 5; j++) { gr0[rg * 5 + j] = acc0[j];
                                    gr1[rg * 5 + j] = acc1[j]; }
    }
    asm volatile("s_waitcnt lgkmcnt(0)" ::: "memory");
    // gates / state / IO
    if (isU) {
      float gi = mygr[u] + bi;
      float gf = mygr[20 + u] + bf;
      float gg = mygr[40 + u] + bg;
      float go = mygr[60 + u] + bo;
      float cu = sigf(gf) * c + sigf(gi) * tanhf_fast(gg);
      c = cu;
      float h = sigf(go) * tanhf_fast(cu);
      seq[(size_t)t * (N_ * 20) + myn * 20 + u] = h;   // dense 160B/wave
      int col = 20 + u;
      myzb[(col / 10) * 12 + (col % 10)] = h;
    }
    if (t + 1 < T_) {
      if (FIRST) {
        if (lane < 5) raw[lane] = px;
        if (lane >= 32 && lane < 37) raw[5 + (lane - 32)] = px;
        asm volatile("s_waitcnt lgkmcnt(0) vmcnt(0)" ::: "memory");
        if (isU) {
          float a = myraw[0] * e0 + myraw[1] * e1 + myraw[2] * e2 + myraw[3] * e3
                  + myraw[4] * e4;
          myzb[(u / 10) * 12 + (u % 10)] = fmaxf(a, 0.0f);
        }
      } else {
        if (isU) myzb[(u / 10) * 12 + (u % 10)] = px;
      }
    }
    asm volatile("s_waitcnt lgkmcnt(0)" ::: "memory");
  }
}

// ---------------- attention over T, one wave per element ----------------
__global__ void __launch_bounds__(256) attn_kernel(
    const float* __restrict__ seq, const float* __restrict__ w1,
    const float* __restrict__ b1v, const float* __restrict__ w2,
    const float* __restrict__ b2v, float* __restrict__ xh, float* __restrict__ xhn) {
  const int wv = threadIdx.x >> 6;
  const int t = threadIdx.x & 63;
  const int n = (blockIdx.x << 2) + wv;
  const bool act = (t < T_);
  float enc[20];
#pragma unroll
  for (int k = 0; k < 20; k++) enc[k] = 0.0f;
  if (act) {
    const float* p = seq + (t * N_ + n) * H_;
#pragma unroll
    for (int q = 0; q < 5; q++) {
      float4 v = *reinterpret_cast<const float4*>(p + 4 * q);
      enc[4 * q] = v.x; enc[4 * q + 1] = v.y; enc[4 * q + 2] = v.z; enc[4 * q + 3] = v.w;
    }
  }
  float e = -3.0e38f;
  if (act) {
    e = b2v[0];
#pragma unroll 4
    for (int k = 0; k < 64; k++) {
      float s = b1v[k];
      const float* wr = w1 + k * 20;
#pragma unroll
      for (int m = 0; m < 20; m++) s += wr[m] * enc[m];
      s = fmaxf(s, 0.0f);
      e += w2[k] * s;
    }
  }
  float mx = e;
#pragma unroll
  for (int d = 32; d; d >>= 1) mx = fmaxf(mx, __shfl_xor(mx, d, 64));
  float p_ = act ? __expf(e - mx) : 0.0f;
  float sm = p_;
#pragma unroll
  for (int d = 32; d; d >>= 1) sm += __shfl_xor(sm, d, 64);
  float w = __fdividef(p_, sm);
  float a[20];
#pragma unroll
  for (int k = 0; k < 20; k++) a[k] = enc[k] * w;
#pragma unroll
  for (int d = 1; d < 64; d <<= 1) {
#pragma unroll
    for (int k = 0; k < 20; k++) a[k] += __shfl_xor(a[k], d, 64);
  }
  if (t == 0) {
    float* op = xh + n * 20;
    float s2 = 0.0f;
#pragma unroll
    for (int k = 0; k < 20; k++) s2 += a[k] * a[k];
#pragma unroll
    for (int q = 0; q < 5; q++) {
      float4 v; v.x = a[4 * q]; v.y = a[4 * q + 1]; v.z = a[4 * q + 2]; v.w = a[4 * q + 3];
      *reinterpret_cast<float4*>(op + 4 * q) = v;
    }
    xhn[n] = sqrtf(s2);
  }
}

// ---------------- x0 norms ----------------
__global__ void __launch_bounds__(256) x0norm_kernel(const float* __restrict__ x0,
                                                     float* __restrict__ nx0,
                                                     float* __restrict__ rx0) {
  int j = blockIdx.x * 256 + threadIdx.x;
  if (j >= N0_) return;
  float s = 0.f;
#pragma unroll
  for (int k = 0; k < 20; k++) { float v = x0[j * 20 + k]; s += v * v; }
  float nv = sqrtf(s);
  nx0[j] = nv;
  rx0[j] = 1.0f / nv;
}

// ---------------- top-6 cosine, 16 lanes per row ----------------
__device__ __forceinline__ bool better_(float v1, int i1, float v2, int i2) {
  return (v1 > v2) || (v1 == v2 && i1 < i2);
}

__device__ __forceinline__ void merge6(float tv[6], int ti[6], int d) {
  float cv[12]; int ci[12];
#pragma unroll
  for (int z = 0; z < 6; z++) { cv[z] = tv[z]; ci[z] = ti[z]; }
#pragma unroll
  for (int z = 0; z < 6; z++) {
    cv[6 + z] = __shfl_xor(tv[z], d, 64);
    ci[6 + z] = __shfl_xor(ti[z], d, 64);
  }
#pragma unroll
  for (int o = 0; o < 6; o++) {
    float bv = -3.0e38f; int bi = 0x7fffffff; int bm = -1;
#pragma unroll
    for (int m = 0; m < 12; m++) {
      bool bt = better_(cv[m], ci[m], bv, bi);
      if (bt) { bv = cv[m]; bi = ci[m]; bm = m; }
    }
    tv[o] = bv; ti[o] = bi;
#pragma unroll
    for (int m = 0; m < 12; m++) if (m == bm) cv[m] = -3.0e38f;
  }
}

__global__ void __launch_bounds__(256) topk_kernel(
    const float* __restrict__ x0, const float* __restrict__ xh,
    const float* __restrict__ xhn, const float* __restrict__ nx0,
    const float* __restrict__ rx0, int* __restrict__ top5) {
  const int gt = blockIdx.x * 256 + threadIdx.x;
  const int i = gt >> 4, sub = gt & 15;
  float q[20];
  const float* qp = xh + i * 20;
#pragma unroll
  for (int z = 0; z < 5; z++) {
    float4 v = *reinterpret_cast<const float4*>(qp + 4 * z);
    q[4 * z] = v.x; q[4 * z + 1] = v.y; q[4 * z + 2] = v.z; q[4 * z + 3] = v.w;
  }
  float tv[6]; int ti[6];
#pragma unroll
  for (int z = 0; z < 6; z++) { tv[z] = -1.0e30f; ti[z] = 0x7fffffff; }
  for (int j = sub; j < N0_; j += 16) {
    const float* xr = x0 + j * 20;
    float d0 = 0.f;
#pragma unroll
    for (int k = 0; k < 20; k++) d0 += q[k] * xr[k];
    float key = d0 * rx0[j];
    if (key > tv[5]) {       // within-lane j ascending => strict > keeps stability
      tv[5] = key; ti[5] = j;
#pragma unroll
      for (int z = 5; z >= 1; z--) {
        bool sw = better_(tv[z], ti[z], tv[z - 1], ti[z - 1]);
        if (sw) {
          float fv = tv[z]; tv[z] = tv[z - 1]; tv[z - 1] = fv;
          int iv = ti[z]; ti[z] = ti[z - 1]; ti[z - 1] = iv;
        }
      }
    }
  }
  merge6(tv, ti, 1);
  merge6(tv, ti, 2);
  merge6(tv, ti, 4);
  merge6(tv, ti, 8);
  if (sub == 0) {
    const float* xr = x0 + ti[0] * 20;
    float d0 = 0.f;
#pragma unroll
    for (int k = 0; k < 20; k++) d0 += q[k] * xr[k];
    float a = (d0 / xhn[i]) / nx0[ti[0]];   // replicate ref's exact-match branch
    int base = (a == 1.0f) ? 1 : 0;
#pragma unroll
    for (int z = 0; z < 5; z++) top5[i * 5 + z] = ti[base + z];
  }
}

// ---------------- SAGE layer-1 aggregation over edge_0 ----------------
__global__ void __launch_bounds__(256) scatter_kernel(const int* __restrict__ edge,
                                                      const float* __restrict__ x0,
                                                      float* sum1, float* cnt1) {
  int e = blockIdx.x * 256 + threadIdx.x;
  if (e >= E0_) return;
  int s = edge[e], d = edge[E0_ + e];
  const float* xr = x0 + s * 20;
  float* dr = sum1 + d * 20;
#pragma unroll
  for (int k = 0; k < 20; k++) atomicAdd(dr + k, xr[k]);
  atomicAdd(cnt1 + d, 1.0f);
}

__global__ void __launch_bounds__(256) base_kernel(
    const float* __restrict__ x0, const float* __restrict__ sum1,
    const float* __restrict__ cnt1, const float* __restrict__ w1l,
    const float* __restrict__ w1r, const float* __restrict__ b1,
    float* __restrict__ obase) {
  int j = blockIdx.x * 256 + threadIdx.x;
  if (j >= N0_) return;
  float cm = fmaxf(cnt1[j], 1.0f);
  float mean[20], xv[20];
#pragma unroll
  for (int k = 0; k < 20; k++) {
    mean[k] = sum1[j * 20 + k] / cm;
    xv[k] = x0[j * 20 + k];
  }
#pragma unroll
  for (int c = 0; c < HC_; c++) {
    float a = b1[c];
#pragma unroll
    for (int k = 0; k < 20; k++) a += mean[k] * w1l[c * 20 + k];
#pragma unroll
    for (int k = 0; k < 20; k++) a += xv[k] * w1r[c * 20 + k];
    obase[j * HC_ + c] = fmaxf(a, 0.0f);
  }
}

// ---------------- SAGE layer-2 at new nodes + linear + softmax ----------------
__global__ void __launch_bounds__(256) final_kernel(
    const float* __restrict__ xh, const int* __restrict__ top5,
    const float* __restrict__ obase, const float* __restrict__ w1r,
    const float* __restrict__ b1, const float* __restrict__ w2l,
    const float* __restrict__ w2r, const float* __restrict__ b2,
    const float* __restrict__ wlin, const float* __restrict__ blin,
    float* __restrict__ out) {
  int n = blockIdx.x * 256 + threadIdx.x;
  if (n >= N_) return;
  float xq[20];
#pragma unroll
  for (int k = 0; k < 20; k++) xq[k] = xh[n * 20 + k];
  float onw[15];   // layer-1 output at this new node (mean = 0: no incoming edge_0)
#pragma unroll
  for (int c = 0; c < HC_; c++) {
    float a = b1[c];
#pragma unroll
    for (int k = 0; k < 20; k++) a += xq[k] * w1r[c * 20 + k];
    onw[c] = fmaxf(a, 0.0f);
  }
  float mean[15];
#pragma unroll
  for (int c = 0; c < HC_; c++) mean[c] = 0.0f;
#pragma unroll
  for (int z = 0; z < K_; z++) {
    int idx = top5[n * 5 + z];
#pragma unroll
    for (int c = 0; c < HC_; c++) mean[c] += obase[idx * HC_ + c];
  }
#pragma unroll
  for (int c = 0; c < HC_; c++) mean[c] = mean[c] / 5.0f;
  float lg[3];
#pragma unroll
  for (int cl = 0; cl < 3; cl++) lg[cl] = blin[cl];
#pragma unroll
  for (int dd = 0; dd < 20; dd++) {
    float v = b2[dd];
#pragma unroll
    for (int c = 0; c < HC_; c++) v += mean[c] * w2l[dd * HC_ + c] + onw[c] * w2r[dd * HC_ + c];
#pragma unroll
    for (int cl = 0; cl < 3; cl++) lg[cl] += v * wlin[cl * 20 + dd];
  }
  float m = fmaxf(lg[0], fmaxf(lg[1], lg[2]));
  float e0 = expf(lg[0] - m), e1 = expf(lg[1] - m), e2 = expf(lg[2] - m);
  float s = e0 + e1 + e2;
  out[n * 3 + 0] = e0 / s;
  out[n * 3 + 1] = e1 / s;
  out[n * 3 + 2] = e2 / s;
}

extern "C" void kernel_launch(void* const* d_in, const int* in_sizes, int n_in,
                              void* d_out, int out_size, void* d_ws, size_t ws_size,
                              hipStream_t stream) {
  const float* x    = (const float*)d_in[0];
  const float* x0   = (const float*)d_in[1];
  const float* embw = (const float*)d_in[2];
  const float* Wih  = (const float*)d_in[3];
  const float* Whh  = (const float*)d_in[4];
  const float* bih  = (const float*)d_in[5];
  const float* bhh  = (const float*)d_in[6];
  const float* aw1  = (const float*)d_in[7];
  const float* ab1  = (const float*)d_in[8];
  const float* aw2  = (const float*)d_in[9];
  const float* ab2  = (const float*)d_in[10];
  const float* w1l  = (const float*)d_in[11];
  const float* w1r  = (const float*)d_in[12];
  const float* b1   = (const float*)d_in[13];
  const float* w2l  = (const float*)d_in[14];
  const float* w2r  = (const float*)d_in[15];
  const float* b2   = (const float*)d_in[16];
  const float* wlin = (const float*)d_in[17];
  const float* blin = (const float*)d_in[18];
  const int* edge0  = (const int*)d_in[19];

  float* ws    = (float*)d_ws;
  float* seq   = ws + OFF_SEQ;
  float* xh    = ws + OFF_XH;
  float* xhn   = ws + OFF_XHN;
  float* nx0   = ws + OFF_NX0;
  float* rx0   = ws + OFF_RX0;
  int*   top5  = (int*)(ws + OFF_TOP5);
  float* sum1  = ws + OFF_SUM1;
  float* cnt1  = ws + OFF_CNT1;
  float* obase = ws + OFF_OBASE;
  float* out   = (float*)d_out;

  hipMemsetAsync(sum1, 0, (size_t)(N0_ * H_ + N0_) * sizeof(float), stream);
  lstm_wpe2_kernel<true><<<N_ / 8, 256, 0, stream>>>(x, embw, Wih, Whh, bih, bhh, seq);
  for (int l = 1; l < 4; l++)
    lstm_wpe2_kernel<false><<<N_ / 8, 256, 0, stream>>>(x, embw, Wih + l * 1600,
                                                        Whh + l * 1600, bih + l * 80,
                                                        bhh + l * 80, seq);
  attn_kernel<<<N_ / 4, 256, 0, stream>>>(seq, aw1, ab1, aw2, ab2, xh, xhn);
  x0norm_kernel<<<(N0_ + 255) / 256, 256, 0, stream>>>(x0, nx0, rx0);
  topk_kernel<<<(N_ * 16) / 256, 256, 0, stream>>>(x0, xh, xhn, nx0, rx0, top5);
  scatter_kernel<<<(E0_ + 255) / 256, 256, 0, stream>>>(edge0, x0, sum1, cnt1);
  base_kernel<<<(N0_ + 255) / 256, 256, 0, stream>>>(x0, sum1, cnt1, w1l, w1r, b1, obase);
  final_kernel<<<N_ / 256, 256, 0, stream>>>(xh, top5, obase, w1r, b1, w2l, w2r, b2,
                                             wlin, blin, out);
}